// Round 5
// baseline (333.864 us; speedup 1.0000x reference)
//
#include <hip/hip_runtime.h>
#include <stdint.h>

typedef __attribute__((ext_vector_type(8))) short bf16x8;
typedef __attribute__((ext_vector_type(4))) float f32x4;

__device__ __forceinline__ unsigned short f32_to_bf16(float f) {
  union { float f; unsigned int u; } v; v.f = f;
  unsigned int u = v.u;
  u += 0x7fffu + ((u >> 16) & 1u);   // round-to-nearest-even
  return (unsigned short)(u >> 16);
}

__device__ __forceinline__ void gload_lds16(const unsigned short* g, unsigned short* lds_p) {
  __builtin_amdgcn_global_load_lds(
      (const __attribute__((address_space(1))) unsigned int*)g,
      (__attribute__((address_space(3))) unsigned int*)lds_p,
      16, 0, 0);
}

// ---------------------------------------------------------------------------
// C[M,N] = scale * A[M,K] x B[N,K]^T (bf16 ushort, K-contiguous rows).
// 128x128 tile, 256 thr = 4 waves of 64x64, m97 2-barrier loop, 32 KB LDS.
// KEY CHANGE r5: __launch_bounds__(256,4) -> 4 resident blocks/CU (was 2).
// m102/m114 evidence: this structure's throughput is set by cross-block
// MFMA/staging overlap (1 blk/CU = 320 TF, 3-4 blk/CU = 833+ TF at same code).
// LDS conflict-free swizzle (proven correct r2-r4): logical chunk (row,k8) at
// physical k8' = k8 ^ ((row>>1)&3); staging pre-swizzles the GLOBAL k-offset
// (kc0) keeping the LDS dest linear for global_load_lds; read side q8s is a
// per-thread constant.
// T1 XCD swizzle: physical block f (round-robin over 8 XCDs, f%8) takes
// logical work (f%8)*(nwg/8) + f/8  -> each XCD runs a contiguous logical
// chunk; consecutive logical ids share the same B-panel (x-fastest) -> B
// loaded ~once per XCD L2. All grids have nwg (per z) divisible by 8.
// ---------------------------------------------------------------------------
template<int MODE>
__global__ __launch_bounds__(256, 4)
void gemm_bt(const unsigned short* __restrict__ A,
             const unsigned short* __restrict__ Bm,
             void* __restrict__ Cv,
             int M, int N, int K, int lda, int ldb, int ldc,
             long sA_, long sB_, long sC_,
             float scale)
{
  __shared__ unsigned short sA[2 * 128 * 32];
  __shared__ unsigned short sB[2 * 128 * 32];

  const int bz = blockIdx.z;
  const unsigned short* Ab = A + (long)bz * sA_;
  const unsigned short* Bb = Bm + (long)bz * sB_;

  // T1: XCD-aware remap of (x,y) within this z-plane.
  const int nx = gridDim.x;
  const int nwg = nx * gridDim.y;            // divisible by 8 for all launches
  const int f = blockIdx.y * nx + blockIdx.x;
  const int cpx = nwg >> 3;
  const int sw = (f & 7) * cpx + (f >> 3);
  const int m0 = (sw % nx) * 128;
  const int n0 = (sw / nx) * 128;

  const int t = threadIdx.x;       // 0..255
  const int lane = t & 63;
  const int w = t >> 6;            // 0..3 -> 2x2 grid of 64x64 subtiles
  const int wr = (w >> 1) * 64;
  const int wc = (w & 1) * 64;
  const int lrow = lane & 15;
  const int q8s = ((lane >> 4) ^ ((lrow >> 1) & 3)) * 8;   // swizzled k-chunk

  const int row0 = t >> 2;
  const int kc0 = ((t & 3) ^ ((t >> 3) & 3)) * 8;          // pre-swizzled global k
  const unsigned short* Ap = Ab + (long)(m0 + row0) * lda + kc0;
  const unsigned short* Bp = Bb + (long)(n0 + row0) * ldb + kc0;
  const long a64 = (long)lda * 64;
  const long b64 = (long)ldb * 64;

  f32x4 acc[4][4];
#pragma unroll
  for (int i = 0; i < 4; ++i)
#pragma unroll
    for (int j = 0; j < 4; ++j)
      acc[i][j] = (f32x4){0.f, 0.f, 0.f, 0.f};

  for (int k0 = 0; k0 < K; k0 += 64) {
    __syncthreads();
#pragma unroll
    for (int s = 0; s < 2; ++s) {
      const int gk = k0 + s * 32;
      gload_lds16(Ap + gk,       &sA[s * 4096 + t * 8]);
      gload_lds16(Ap + a64 + gk, &sA[s * 4096 + t * 8 + 2048]);
      gload_lds16(Bp + gk,       &sB[s * 4096 + t * 8]);
      gload_lds16(Bp + b64 + gk, &sB[s * 4096 + t * 8 + 2048]);
    }
    __syncthreads();

#pragma unroll
    for (int s = 0; s < 2; ++s) {
      bf16x8 af[4], bf[4];
#pragma unroll
      for (int i = 0; i < 4; ++i) {
        af[i] = *(const bf16x8*)&sA[s * 4096 + (wr + i * 16 + lrow) * 32 + q8s];
        bf[i] = *(const bf16x8*)&sB[s * 4096 + (wc + i * 16 + lrow) * 32 + q8s];
      }
#pragma unroll
      for (int mi = 0; mi < 4; ++mi)
#pragma unroll
        for (int ni = 0; ni < 4; ++ni)
          acc[mi][ni] = __builtin_amdgcn_mfma_f32_16x16x32_bf16(af[mi], bf[ni], acc[mi][ni], 0, 0, 0);
    }
  }

  // epilogue: C/D layout col = lane&15, row = (lane>>4)*4 + reg
  const int cl = lane & 15;
  const int rq = (lane >> 4) * 4;

  if (MODE == 2) {
    float* Cb = (float*)Cv + (long)bz * sC_;
#pragma unroll
    for (int mi = 0; mi < 4; ++mi) {
      const int rowb = m0 + wr + mi * 16 + rq;
#pragma unroll
      for (int ni = 0; ni < 4; ++ni) {
        const int col = n0 + wc + ni * 16 + cl;
#pragma unroll
        for (int r = 0; r < 4; ++r)
          Cb[(long)(rowb + r) * ldc + col] = acc[mi][ni][r] * scale;
      }
    }
  } else {
    unsigned short* Cb = (unsigned short*)Cv + (long)bz * sC_;
#pragma unroll
    for (int mi = 0; mi < 4; ++mi) {
      const int rowb = m0 + wr + mi * 16 + rq;
#pragma unroll
      for (int ni = 0; ni < 4; ++ni) {
        const int col = n0 + wc + ni * 16 + cl;
#pragma unroll
        for (int r = 0; r < 4; ++r)
          Cb[(long)(rowb + r) * ldc + col] = f32_to_bf16(acc[mi][ni][r]);
      }
    }
  }
}

// softmax over rows of 2048 fp32 -> bf16
__global__ __launch_bounds__(256)
void softmax_rows(const float* __restrict__ dist, unsigned short* __restrict__ attn) {
  const long row = blockIdx.x;
  const float4* in = (const float4*)(dist + row * 2048);
  const int t = threadIdx.x;
  float4 v0 = in[t];
  float4 v1 = in[t + 256];

  float m = fmaxf(fmaxf(fmaxf(v0.x, v0.y), fmaxf(v0.z, v0.w)),
                  fmaxf(fmaxf(v1.x, v1.y), fmaxf(v1.z, v1.w)));
#pragma unroll
  for (int off = 32; off > 0; off >>= 1)
    m = fmaxf(m, __shfl_xor(m, off, 64));

  __shared__ float redm[4];
  __shared__ float reds[4];
  if ((t & 63) == 0) redm[t >> 6] = m;
  __syncthreads();
  m = fmaxf(fmaxf(redm[0], redm[1]), fmaxf(redm[2], redm[3]));

  float e[8];
  e[0] = __expf(v0.x - m); e[1] = __expf(v0.y - m);
  e[2] = __expf(v0.z - m); e[3] = __expf(v0.w - m);
  e[4] = __expf(v1.x - m); e[5] = __expf(v1.y - m);
  e[6] = __expf(v1.z - m); e[7] = __expf(v1.w - m);

  float s = ((e[0] + e[1]) + (e[2] + e[3])) + ((e[4] + e[5]) + (e[6] + e[7]));
#pragma unroll
  for (int off = 32; off > 0; off >>= 1)
    s += __shfl_xor(s, off, 64);
  if ((t & 63) == 0) reds[t >> 6] = s;
  __syncthreads();
  s = (reds[0] + reds[1]) + (reds[2] + reds[3]);

  const float inv = 1.0f / s;
  ushort4 o0, o1;
  o0.x = f32_to_bf16(e[0] * inv); o0.y = f32_to_bf16(e[1] * inv);
  o0.z = f32_to_bf16(e[2] * inv); o0.w = f32_to_bf16(e[3] * inv);
  o1.x = f32_to_bf16(e[4] * inv); o1.y = f32_to_bf16(e[5] * inv);
  o1.z = f32_to_bf16(e[6] * inv); o1.w = f32_to_bf16(e[7] * inv);
  *(ushort4*)(attn + row * 2048 + t * 4) = o0;
  *(ushort4*)(attn + row * 2048 + 1024 + t * 4) = o1;
}

// Fused cast of Wq,Wk,Wv,Wo (1M elems each) + x (8M elems) -> contiguous bf16.
__global__ __launch_bounds__(256)
void cast_all(const float* __restrict__ Wq, const float* __restrict__ Wk,
              const float* __restrict__ Wv, const float* __restrict__ Wo,
              const float* __restrict__ x, unsigned short* __restrict__ dst) {
  const long i = ((long)blockIdx.x * 256 + threadIdx.x) * 4;
  const float* src;
  long off;
  if (i < 4194304) {
    const int which = (int)(i >> 20);
    src = (which == 0) ? Wq : (which == 1) ? Wk : (which == 2) ? Wv : Wo;
    off = i & 1048575;
  } else {
    src = x;
    off = i - 4194304;
  }
  float4 v = *(const float4*)(src + off);
  ushort4 o;
  o.x = f32_to_bf16(v.x); o.y = f32_to_bf16(v.y);
  o.z = f32_to_bf16(v.z); o.w = f32_to_bf16(v.w);
  *(ushort4*)(dst + i) = o;
}

extern "C" void kernel_launch(void* const* d_in, const int* in_sizes, int n_in,
                              void* d_out, int out_size, void* d_ws, size_t ws_size,
                              hipStream_t stream) {
  const float* x  = (const float*)d_in[0];
  const float* Wq = (const float*)d_in[1];
  const float* Wk = (const float*)d_in[2];
  const float* Wv = (const float*)d_in[3];
  const float* Wo = (const float*)d_in[4];

  const long Bn = 4, S = 2048, D = 1024;
  const long MS = Bn * S;               // 8192

  float* out_p  = (float*)d_out;        // [B,S,D] = 8192x1024 fp32
  float* weight = out_p + MS * D;       // [B,S,S] = 4x2048x2048 fp32

  // workspace layout (ushort elements):
  unsigned short* Wqb = (unsigned short*)d_ws;   // [2048,1024]: Wq rows then Wk rows
  unsigned short* Wvb = Wqb + 2 * D * D;
  unsigned short* Wob = Wvb + D * D;
  unsigned short* xb  = Wob + D * D;    // [8192,1024]
  unsigned short* qk  = xb + MS * D;    // [8192,2048]: cols 0..1023 = q, 1024.. = k
  unsigned short* vtb = qk + MS * 2048; // [1024][8192]  (vT, cols = b*2048 + s)
  unsigned short* attn = qk;            // alias (qk dead after dist)
  unsigned short* ctx  = xb;            // alias (xb dead after v GEMM)

  cast_all<<<12288, 256, 0, stream>>>(Wq, Wk, Wv, Wo, x, Wqb);

  // qk = x [Wq;Wk]^T  (8192 x 2048 x 1024)               grid 1024 = 4/CU
  gemm_bt<0><<<dim3(64, 16, 1), 256, 0, stream>>>(xb, Wqb, qk, 8192, 2048, 1024,
                                                  1024, 1024, 2048, 0, 0, 0, 1.f);
  // vT = Wv x^T : M=1024, N=8192 (all batches merged)    grid 512
  gemm_bt<0><<<dim3(8, 64, 1), 256, 0, stream>>>(Wvb, xb, vtb, 1024, 8192, 1024,
                                                 1024, 1024, 8192, 0, 0, 0, 1.f);
  // dist[b] = scale * q[b] k[b]^T -> fp32                grid 1024
  gemm_bt<2><<<dim3(16, 16, 4), 256, 0, stream>>>(qk, qk + 1024, weight, 2048, 2048, 1024,
                                                  2048, 2048, 2048,
                                                  S * 2048, S * 2048, S * S,
                                                  0.04419417382415922f);
  // attn = softmax(dist) -> bf16
  softmax_rows<<<(int)(Bn * S), 256, 0, stream>>>(weight, attn);
  // ctx[b] = attn[b] vT[:, b*2048:]^T : M=2048, N=1024, K=2048   grid 512
  gemm_bt<0><<<dim3(16, 8, 4), 256, 0, stream>>>(attn, vtb, ctx, 2048, 1024, 2048,
                                                 2048, 8192, 1024,
                                                 S * S, 2048, S * D, 1.f);
  // out = ctx Wo^T -> fp32                               grid 512
  gemm_bt<2><<<dim3(64, 8, 1), 256, 0, stream>>>(ctx, Wob, out_p, 8192, 1024, 1024,
                                                 1024, 1024, 1024, 0, 0, 0, 1.f);
}

// Round 6
// 316.594 us; speedup vs baseline: 1.0546x; 1.0546x over previous
//
#include <hip/hip_runtime.h>
#include <stdint.h>

typedef __attribute__((ext_vector_type(8))) short bf16x8;
typedef __attribute__((ext_vector_type(4))) float f32x4;

__device__ __forceinline__ unsigned short f32_to_bf16(float f) {
  union { float f; unsigned int u; } v; v.f = f;
  unsigned int u = v.u;
  u += 0x7fffu + ((u >> 16) & 1u);   // round-to-nearest-even
  return (unsigned short)(u >> 16);
}

__device__ __forceinline__ void gload_lds16(const unsigned short* g, unsigned short* lds_p) {
  __builtin_amdgcn_global_load_lds(
      (const __attribute__((address_space(1))) unsigned int*)g,
      (__attribute__((address_space(3))) unsigned int*)lds_p,
      16, 0, 0);
}

// ---------------------------------------------------------------------------
// C[M,N] = scale * A[M,K] x B[N,K]^T (bf16 ushort, K-contiguous rows).
// LDS-BW analysis (r6): fragment read volume is geometric (per wave:
// (A-rows + B-cols) x K), so the only lever on the LDS-bytes/FLOP ratio is
// per-wave output area.  64x64 waves: 96 KB LDS traffic per 128^2-tile K-step
// vs 620 cy of MFMA -> LDS-bound at ~0.55-0.8 (the observed ~37% MfmaUtil
// ceiling of every prior round).  128x64 waves cut bytes/FLOP 1.5x.
// gemm_w: 256x128 tile, 4 waves of 128x64 (acc[8][4]=128 VGPR), 48 KB LDS
//   single-staged, plain 2-sync loop, 2 blocks/CU for cross-block overlap.
// gemm_n: 128x128 tile, 4 waves of 64x64 (r4 config) for narrow shapes.
// Both: conflict-free both-sides swizzle (proven r2-r5): logical chunk
// (row,k8) at physical k8' = k8 ^ ((row>>1)&3); staging pre-swizzles the
// GLOBAL k-offset (kc0 = ((t&3)^((t>>3)&3))*8, invariant under row+64n),
// LDS dest stays linear for global_load_lds; read side
// q8s = ((lane>>4)^((lrow>>1)&3))*8 is a per-thread constant.
// ---------------------------------------------------------------------------

// ============================ 256x128, big waves ===========================
template<int MODE>
__global__ __launch_bounds__(256, 2)
void gemm_w(const unsigned short* __restrict__ A,
            const unsigned short* __restrict__ Bm,
            void* __restrict__ Cv,
            int M, int N, int K, int lda, int ldb, int ldc,
            long sA_, long sB_, long sC_,
            float scale)
{
  __shared__ unsigned short sA[2 * 256 * 32];   // 32 KB: 2 k-half panels
  __shared__ unsigned short sB[2 * 128 * 32];   // 16 KB

  const int bz = blockIdx.z;
  const unsigned short* Ab = A + (long)bz * sA_;
  const unsigned short* Bb = Bm + (long)bz * sB_;

  const int m0 = blockIdx.x * 256;
  const int n0 = blockIdx.y * 128;

  const int t = threadIdx.x;       // 0..255
  const int lane = t & 63;
  const int w = t >> 6;            // 0..3 -> 2x2 grid of 128x64 subtiles
  const int wr = (w >> 1) * 128;
  const int wc = (w & 1) * 64;
  const int lrow = lane & 15;
  const int q8s = ((lane >> 4) ^ ((lrow >> 1) & 3)) * 8;   // swizzled k-chunk

  const int row0 = t >> 2;
  const int kc0 = ((t & 3) ^ ((t >> 3) & 3)) * 8;          // pre-swizzled global k
  const unsigned short* Ap = Ab + (long)(m0 + row0) * lda + kc0;
  const unsigned short* Bp = Bb + (long)(n0 + row0) * ldb + kc0;
  const long a64 = (long)lda * 64;
  const long b64 = (long)ldb * 64;

  f32x4 acc[8][4];
#pragma unroll
  for (int i = 0; i < 8; ++i)
#pragma unroll
    for (int j = 0; j < 4; ++j)
      acc[i][j] = (f32x4){0.f, 0.f, 0.f, 0.f};

  for (int k0 = 0; k0 < K; k0 += 64) {
    __syncthreads();
#pragma unroll
    for (int s = 0; s < 2; ++s) {
      const int gk = k0 + s * 32;
      // A: 256 rows as 4 groups of 64 (thread t -> rows t>>2 + {0,64,128,192})
      gload_lds16(Ap + gk,           &sA[s * 8192 + t * 8]);
      gload_lds16(Ap + a64 + gk,     &sA[s * 8192 + t * 8 + 2048]);
      gload_lds16(Ap + 2 * a64 + gk, &sA[s * 8192 + t * 8 + 4096]);
      gload_lds16(Ap + 3 * a64 + gk, &sA[s * 8192 + t * 8 + 6144]);
      // B: 128 rows as 2 groups of 64
      gload_lds16(Bp + gk,           &sB[s * 4096 + t * 8]);
      gload_lds16(Bp + b64 + gk,     &sB[s * 4096 + t * 8 + 2048]);
    }
    __syncthreads();

#pragma unroll
    for (int s = 0; s < 2; ++s) {
      bf16x8 af[8], bf[4];
#pragma unroll
      for (int i = 0; i < 8; ++i)
        af[i] = *(const bf16x8*)&sA[s * 8192 + (wr + i * 16 + lrow) * 32 + q8s];
#pragma unroll
      for (int n = 0; n < 4; ++n)
        bf[n] = *(const bf16x8*)&sB[s * 4096 + (wc + n * 16 + lrow) * 32 + q8s];
#pragma unroll
      for (int mi = 0; mi < 8; ++mi)
#pragma unroll
        for (int ni = 0; ni < 4; ++ni)
          acc[mi][ni] = __builtin_amdgcn_mfma_f32_16x16x32_bf16(af[mi], bf[ni], acc[mi][ni], 0, 0, 0);
    }
  }

  // epilogue: C/D layout col = lane&15, row = (lane>>4)*4 + reg
  const int cl = lane & 15;
  const int rq = (lane >> 4) * 4;

  if (MODE == 2) {
    float* Cb = (float*)Cv + (long)bz * sC_;
#pragma unroll
    for (int mi = 0; mi < 8; ++mi) {
      const int rowb = m0 + wr + mi * 16 + rq;
#pragma unroll
      for (int ni = 0; ni < 4; ++ni) {
        const int col = n0 + wc + ni * 16 + cl;
#pragma unroll
        for (int r = 0; r < 4; ++r)
          Cb[(long)(rowb + r) * ldc + col] = acc[mi][ni][r] * scale;
      }
    }
  } else {
    unsigned short* Cb = (unsigned short*)Cv + (long)bz * sC_;
#pragma unroll
    for (int mi = 0; mi < 8; ++mi) {
      const int rowb = m0 + wr + mi * 16 + rq;
#pragma unroll
      for (int ni = 0; ni < 4; ++ni) {
        const int col = n0 + wc + ni * 16 + cl;
#pragma unroll
        for (int r = 0; r < 4; ++r)
          Cb[(long)(rowb + r) * ldc + col] = f32_to_bf16(acc[mi][ni][r]);
      }
    }
  }
}

// ============================ 128x128 variant ==============================
template<int MODE>
__global__ __launch_bounds__(256, 2)
void gemm_n(const unsigned short* __restrict__ A,
            const unsigned short* __restrict__ Bm,
            void* __restrict__ Cv,
            int M, int N, int K, int lda, int ldb, int ldc,
            long sA_, long sB_, long sC_,
            float scale)
{
  __shared__ unsigned short sA[2 * 128 * 32];
  __shared__ unsigned short sB[2 * 128 * 32];

  const int bz = blockIdx.z;
  const unsigned short* Ab = A + (long)bz * sA_;
  const unsigned short* Bb = Bm + (long)bz * sB_;

  const int m0 = blockIdx.x * 128;
  const int n0 = blockIdx.y * 128;

  const int t = threadIdx.x;       // 0..255
  const int lane = t & 63;
  const int w = t >> 6;            // 0..3 -> 2x2 grid of 64x64 subtiles
  const int wr = (w >> 1) * 64;
  const int wc = (w & 1) * 64;
  const int lrow = lane & 15;
  const int q8s = ((lane >> 4) ^ ((lrow >> 1) & 3)) * 8;

  const int row0 = t >> 2;
  const int kc0 = ((t & 3) ^ ((t >> 3) & 3)) * 8;
  const unsigned short* Ap = Ab + (long)(m0 + row0) * lda + kc0;
  const unsigned short* Bp = Bb + (long)(n0 + row0) * ldb + kc0;
  const long a64 = (long)lda * 64;
  const long b64 = (long)ldb * 64;

  f32x4 acc[4][4];
#pragma unroll
  for (int i = 0; i < 4; ++i)
#pragma unroll
    for (int j = 0; j < 4; ++j)
      acc[i][j] = (f32x4){0.f, 0.f, 0.f, 0.f};

  for (int k0 = 0; k0 < K; k0 += 64) {
    __syncthreads();
#pragma unroll
    for (int s = 0; s < 2; ++s) {
      const int gk = k0 + s * 32;
      gload_lds16(Ap + gk,       &sA[s * 4096 + t * 8]);
      gload_lds16(Ap + a64 + gk, &sA[s * 4096 + t * 8 + 2048]);
      gload_lds16(Bp + gk,       &sB[s * 4096 + t * 8]);
      gload_lds16(Bp + b64 + gk, &sB[s * 4096 + t * 8 + 2048]);
    }
    __syncthreads();

#pragma unroll
    for (int s = 0; s < 2; ++s) {
      bf16x8 af[4], bf[4];
#pragma unroll
      for (int i = 0; i < 4; ++i) {
        af[i] = *(const bf16x8*)&sA[s * 4096 + (wr + i * 16 + lrow) * 32 + q8s];
        bf[i] = *(const bf16x8*)&sB[s * 4096 + (wc + i * 16 + lrow) * 32 + q8s];
      }
#pragma unroll
      for (int mi = 0; mi < 4; ++mi)
#pragma unroll
        for (int ni = 0; ni < 4; ++ni)
          acc[mi][ni] = __builtin_amdgcn_mfma_f32_16x16x32_bf16(af[mi], bf[ni], acc[mi][ni], 0, 0, 0);
    }
  }

  const int cl = lane & 15;
  const int rq = (lane >> 4) * 4;

  if (MODE == 2) {
    float* Cb = (float*)Cv + (long)bz * sC_;
#pragma unroll
    for (int mi = 0; mi < 4; ++mi) {
      const int rowb = m0 + wr + mi * 16 + rq;
#pragma unroll
      for (int ni = 0; ni < 4; ++ni) {
        const int col = n0 + wc + ni * 16 + cl;
#pragma unroll
        for (int r = 0; r < 4; ++r)
          Cb[(long)(rowb + r) * ldc + col] = acc[mi][ni][r] * scale;
      }
    }
  } else {
    unsigned short* Cb = (unsigned short*)Cv + (long)bz * sC_;
#pragma unroll
    for (int mi = 0; mi < 4; ++mi) {
      const int rowb = m0 + wr + mi * 16 + rq;
#pragma unroll
      for (int ni = 0; ni < 4; ++ni) {
        const int col = n0 + wc + ni * 16 + cl;
#pragma unroll
        for (int r = 0; r < 4; ++r)
          Cb[(long)(rowb + r) * ldc + col] = f32_to_bf16(acc[mi][ni][r]);
      }
    }
  }
}

// softmax over rows of 2048 fp32 -> bf16
__global__ __launch_bounds__(256)
void softmax_rows(const float* __restrict__ dist, unsigned short* __restrict__ attn) {
  const long row = blockIdx.x;
  const float4* in = (const float4*)(dist + row * 2048);
  const int t = threadIdx.x;
  float4 v0 = in[t];
  float4 v1 = in[t + 256];

  float m = fmaxf(fmaxf(fmaxf(v0.x, v0.y), fmaxf(v0.z, v0.w)),
                  fmaxf(fmaxf(v1.x, v1.y), fmaxf(v1.z, v1.w)));
#pragma unroll
  for (int off = 32; off > 0; off >>= 1)
    m = fmaxf(m, __shfl_xor(m, off, 64));

  __shared__ float redm[4];
  __shared__ float reds[4];
  if ((t & 63) == 0) redm[t >> 6] = m;
  __syncthreads();
  m = fmaxf(fmaxf(redm[0], redm[1]), fmaxf(redm[2], redm[3]));

  float e[8];
  e[0] = __expf(v0.x - m); e[1] = __expf(v0.y - m);
  e[2] = __expf(v0.z - m); e[3] = __expf(v0.w - m);
  e[4] = __expf(v1.x - m); e[5] = __expf(v1.y - m);
  e[6] = __expf(v1.z - m); e[7] = __expf(v1.w - m);

  float s = ((e[0] + e[1]) + (e[2] + e[3])) + ((e[4] + e[5]) + (e[6] + e[7]));
#pragma unroll
  for (int off = 32; off > 0; off >>= 1)
    s += __shfl_xor(s, off, 64);
  if ((t & 63) == 0) reds[t >> 6] = s;
  __syncthreads();
  s = (reds[0] + reds[1]) + (reds[2] + reds[3]);

  const float inv = 1.0f / s;
  ushort4 o0, o1;
  o0.x = f32_to_bf16(e[0] * inv); o0.y = f32_to_bf16(e[1] * inv);
  o0.z = f32_to_bf16(e[2] * inv); o0.w = f32_to_bf16(e[3] * inv);
  o1.x = f32_to_bf16(e[4] * inv); o1.y = f32_to_bf16(e[5] * inv);
  o1.z = f32_to_bf16(e[6] * inv); o1.w = f32_to_bf16(e[7] * inv);
  *(ushort4*)(attn + row * 2048 + t * 4) = o0;
  *(ushort4*)(attn + row * 2048 + 1024 + t * 4) = o1;
}

// Fused cast of Wq,Wk,Wv,Wo (1M elems each) + x (8M elems) -> contiguous bf16.
__global__ __launch_bounds__(256)
void cast_all(const float* __restrict__ Wq, const float* __restrict__ Wk,
              const float* __restrict__ Wv, const float* __restrict__ Wo,
              const float* __restrict__ x, unsigned short* __restrict__ dst) {
  const long i = ((long)blockIdx.x * 256 + threadIdx.x) * 4;
  const float* src;
  long off;
  if (i < 4194304) {
    const int which = (int)(i >> 20);
    src = (which == 0) ? Wq : (which == 1) ? Wk : (which == 2) ? Wv : Wo;
    off = i & 1048575;
  } else {
    src = x;
    off = i - 4194304;
  }
  float4 v = *(const float4*)(src + off);
  ushort4 o;
  o.x = f32_to_bf16(v.x); o.y = f32_to_bf16(v.y);
  o.z = f32_to_bf16(v.z); o.w = f32_to_bf16(v.w);
  *(ushort4*)(dst + i) = o;
}

extern "C" void kernel_launch(void* const* d_in, const int* in_sizes, int n_in,
                              void* d_out, int out_size, void* d_ws, size_t ws_size,
                              hipStream_t stream) {
  const float* x  = (const float*)d_in[0];
  const float* Wq = (const float*)d_in[1];
  const float* Wk = (const float*)d_in[2];
  const float* Wv = (const float*)d_in[3];
  const float* Wo = (const float*)d_in[4];

  const long Bn = 4, S = 2048, D = 1024;
  const long MS = Bn * S;               // 8192

  float* out_p  = (float*)d_out;        // [B,S,D] = 8192x1024 fp32
  float* weight = out_p + MS * D;       // [B,S,S] = 4x2048x2048 fp32

  // workspace layout (ushort elements):
  unsigned short* Wqb = (unsigned short*)d_ws;   // [2048,1024]: Wq rows then Wk rows
  unsigned short* Wvb = Wqb + 2 * D * D;
  unsigned short* Wob = Wvb + D * D;
  unsigned short* xb  = Wob + D * D;    // [8192,1024]
  unsigned short* qk  = xb + MS * D;    // [8192,2048]: cols 0..1023 = q, 1024.. = k
  unsigned short* vtb = qk + MS * 2048; // [1024][8192]  (vT, cols = b*2048 + s)
  unsigned short* attn = qk;            // alias (qk dead after dist)
  unsigned short* ctx  = xb;            // alias (xb dead after v GEMM)

  cast_all<<<12288, 256, 0, stream>>>(Wq, Wk, Wv, Wo, x, Wqb);

  // qk = x [Wq;Wk]^T  (8192 x 2048 x 1024)               grid 512 (256x128)
  gemm_w<0><<<dim3(32, 16, 1), 256, 0, stream>>>(xb, Wqb, qk, 8192, 2048, 1024,
                                                 1024, 1024, 2048, 0, 0, 0, 1.f);
  // vT = Wv x^T : M=1024, N=8192 (all batches merged)    grid 512 (128x128)
  gemm_n<0><<<dim3(8, 64, 1), 256, 0, stream>>>(Wvb, xb, vtb, 1024, 8192, 1024,
                                                1024, 1024, 8192, 0, 0, 0, 1.f);
  // dist[b] = scale * q[b] k[b]^T -> fp32                grid 512 (256x128)
  gemm_w<2><<<dim3(8, 16, 4), 256, 0, stream>>>(qk, qk + 1024, weight, 2048, 2048, 1024,
                                                2048, 2048, 2048,
                                                S * 2048, S * 2048, S * S,
                                                0.04419417382415922f);
  // attn = softmax(dist) -> bf16
  softmax_rows<<<(int)(Bn * S), 256, 0, stream>>>(weight, attn);
  // ctx[b] = attn[b] vT[:, b*2048:]^T : M=2048, N=1024, K=2048   grid 512 (128x128)
  gemm_n<0><<<dim3(16, 8, 4), 256, 0, stream>>>(attn, vtb, ctx, 2048, 1024, 2048,
                                                2048, 8192, 1024,
                                                S * S, 2048, S * D, 1.f);
  // out = ctx Wo^T -> fp32                               grid 512 (128x128)
  gemm_n<2><<<dim3(64, 8, 1), 256, 0, stream>>>(ctx, Wob, out_p, 8192, 1024, 1024,
                                                1024, 1024, 1024, 0, 0, 0, 1.f);
}

// Round 8
// 315.204 us; speedup vs baseline: 1.0592x; 1.0044x over previous
//
#include <hip/hip_runtime.h>
#include <stdint.h>

typedef __attribute__((ext_vector_type(8))) short bf16x8;
typedef __attribute__((ext_vector_type(4))) float f32x4;

__device__ __forceinline__ unsigned short f32_to_bf16(float f) {
  union { float f; unsigned int u; } v; v.f = f;
  unsigned int u = v.u;
  u += 0x7fffu + ((u >> 16) & 1u);   // round-to-nearest-even
  return (unsigned short)(u >> 16);
}

__device__ __forceinline__ void gload_lds16(const unsigned short* g, unsigned short* lds_p) {
  __builtin_amdgcn_global_load_lds(
      (const __attribute__((address_space(1))) unsigned int*)g,
      (__attribute__((address_space(3))) unsigned int*)lds_p,
      16, 0, 0);
}

// ---------------------------------------------------------------------------
// C[M,N] = scale * A[M,K] x B[N,K]^T (bf16 ushort, K-contiguous rows).
// K-loop: r4's verified m97 2-barrier structure + conflict-free both-sides
// swizzle (unchanged, proven r2-r6).
// r7 CHANGE (resubmitted after infra failure; audited OOB/align/barriers):
// OPERAND-SWAPPED MFMA + COALESCED LDS-STAGED EPILOGUE.
//   - acc = mfma(bf, af, acc): per-lane fragment becomes
//     C[m = tile_m + cl][n = tile_n + rq + r] -> 4 CONSECUTIVE n per lane.
//     Staging/LDS reads are operand-symmetric, K-loop byte-identical.
//   - Epilogue: pack 4 vals -> 1 LDS write per (mi,ni) (16/thread), XOR
//     swizzle (<=2-way = free), sync, linear readback: 8
//     global_store_dwordx4/thread, quarter-wave = 256 B contiguous
//     (vs previous 64 scalar stores/thread at 4 rows x 32 B segments).
//     MODE 2 (fp32) runs two 64-row passes in the same 32 KB.
//   Rationale: all six prior schedule variants (308-347 us) shared the
//   scalar epilogue; at K=1024 it is the largest never-changed cost.
// ---------------------------------------------------------------------------
template<int MODE>
__global__ __launch_bounds__(256, 2)
void gemm_bt(const unsigned short* __restrict__ A,
             const unsigned short* __restrict__ Bm,
             void* __restrict__ Cv,
             int M, int N, int K, int lda, int ldb, int ldc,
             long sA_, long sB_, long sC_,
             float scale)
{
  __shared__ unsigned short smem[16384];   // 32 KB: staging sA|sB, then epilogue
  unsigned short* sA = smem;               // [2 panels][128][32]
  unsigned short* sB = smem + 8192;

  const int bz = blockIdx.z;
  const unsigned short* Ab = A + (long)bz * sA_;
  const unsigned short* Bb = Bm + (long)bz * sB_;

  const int m0 = blockIdx.x * 128;
  const int n0 = blockIdx.y * 128;

  const int t = threadIdx.x;       // 0..255
  const int lane = t & 63;
  const int w = t >> 6;            // 0..3 -> 2x2 grid of 64x64 subtiles
  const int wr = (w >> 1) * 64;
  const int wc = (w & 1) * 64;
  const int lrow = lane & 15;
  const int q8s = ((lane >> 4) ^ ((lrow >> 1) & 3)) * 8;   // swizzled k-chunk

  const int row0 = t >> 2;
  const int kc0 = ((t & 3) ^ ((t >> 3) & 3)) * 8;          // pre-swizzled global k
  const unsigned short* Ap = Ab + (long)(m0 + row0) * lda + kc0;
  const unsigned short* Bp = Bb + (long)(n0 + row0) * ldb + kc0;
  const long a64 = (long)lda * 64;
  const long b64 = (long)ldb * 64;

  f32x4 acc[4][4];
#pragma unroll
  for (int i = 0; i < 4; ++i)
#pragma unroll
    for (int j = 0; j < 4; ++j)
      acc[i][j] = (f32x4){0.f, 0.f, 0.f, 0.f};

  for (int k0 = 0; k0 < K; k0 += 64) {
    __syncthreads();
#pragma unroll
    for (int s = 0; s < 2; ++s) {
      const int gk = k0 + s * 32;
      gload_lds16(Ap + gk,       &sA[s * 4096 + t * 8]);
      gload_lds16(Ap + a64 + gk, &sA[s * 4096 + t * 8 + 2048]);
      gload_lds16(Bp + gk,       &sB[s * 4096 + t * 8]);
      gload_lds16(Bp + b64 + gk, &sB[s * 4096 + t * 8 + 2048]);
    }
    __syncthreads();

#pragma unroll
    for (int s = 0; s < 2; ++s) {
      bf16x8 af[4], bf[4];
#pragma unroll
      for (int i = 0; i < 4; ++i) {
        af[i] = *(const bf16x8*)&sA[s * 4096 + (wr + i * 16 + lrow) * 32 + q8s];
        bf[i] = *(const bf16x8*)&sB[s * 4096 + (wc + i * 16 + lrow) * 32 + q8s];
      }
      // swapped operands: D "row" dim <- B (n), D "col" <- A (m)
#pragma unroll
      for (int mi = 0; mi < 4; ++mi)
#pragma unroll
        for (int ni = 0; ni < 4; ++ni)
          acc[mi][ni] = __builtin_amdgcn_mfma_f32_16x16x32_bf16(bf[ni], af[mi], acc[mi][ni], 0, 0, 0);
    }
  }

  // Swapped C/D layout: element = C[m0 + wr + mi*16 + cl][n0 + wc + ni*16 + rq + r]
  const int cl = lane & 15;
  const int rq = (lane >> 4) * 4;

  __syncthreads();   // staging LDS dead; reuse for epilogue

  if (MODE == 2) {
    float* ef = (float*)smem;     // pass = 64 rows x 128 cols fp32 = 32 KB
    float* Cb = (float*)Cv + (long)bz * sC_;
#pragma unroll
    for (int pass = 0; pass < 2; ++pass) {
      if ((w >> 1) == pass) {     // waves with wr == pass*64 own these rows
#pragma unroll
        for (int mi = 0; mi < 4; ++mi) {
          const int mr = mi * 16 + cl;            // row within pass: 0..63
#pragma unroll
          for (int ni = 0; ni < 4; ++ni) {
            const int n16 = (wc + ni * 16 + rq) >> 2;   // 16B chunk 0..31
            const int ph = n16 ^ (mr & 15);
            f32x4 v;
            v[0] = acc[mi][ni][0] * scale; v[1] = acc[mi][ni][1] * scale;
            v[2] = acc[mi][ni][2] * scale; v[3] = acc[mi][ni][3] * scale;
            *(f32x4*)&ef[mr * 128 + ph * 4] = v;
          }
        }
      }
      __syncthreads();
      // readback: 64 rows x 32 chunks of 16B = 2048 chunks, 8 per thread
#pragma unroll
      for (int i = 0; i < 8; ++i) {
        const int c = t + i * 256;
        const int m = c >> 5;
        const int k16 = c & 31;
        const int ph = k16 ^ (m & 15);
        f32x4 v = *(const f32x4*)&ef[m * 128 + ph * 4];
        *(f32x4*)&Cb[(long)(m0 + pass * 64 + m) * ldc + n0 + k16 * 4] = v;
      }
      __syncthreads();
    }
  } else {
    unsigned short* eb = smem;    // 128 rows x 128 cols bf16 = 32 KB
    unsigned short* Cb = (unsigned short*)Cv + (long)bz * sC_;
#pragma unroll
    for (int mi = 0; mi < 4; ++mi) {
      const int mr = wr + mi * 16 + cl;           // 0..127
      const int sw = (mr & 15) << 1;
#pragma unroll
      for (int ni = 0; ni < 4; ++ni) {
        const int p8 = ((wc + ni * 16 + rq) >> 2) ^ sw;   // 8B chunk 0..31
        uint2 pk;
        pk.x = (unsigned)f32_to_bf16(acc[mi][ni][0]) |
               ((unsigned)f32_to_bf16(acc[mi][ni][1]) << 16);
        pk.y = (unsigned)f32_to_bf16(acc[mi][ni][2]) |
               ((unsigned)f32_to_bf16(acc[mi][ni][3]) << 16);
        *(uint2*)&eb[mr * 128 + p8 * 4] = pk;
      }
    }
    __syncthreads();
    // readback: 128 rows x 16 chunks of 16B = 2048 chunks, 8 per thread
#pragma unroll
    for (int i = 0; i < 8; ++i) {
      const int c = t + i * 256;
      const int m = c >> 4;
      const int k16 = c & 15;
      const int ph = k16 ^ (m & 15);
      bf16x8 v = *(const bf16x8*)&eb[m * 128 + ph * 8];
      *(bf16x8*)&Cb[(long)(m0 + m) * ldc + n0 + k16 * 8] = v;
    }
  }
}

// softmax over rows of 2048 fp32 -> bf16
__global__ __launch_bounds__(256)
void softmax_rows(const float* __restrict__ dist, unsigned short* __restrict__ attn) {
  const long row = blockIdx.x;
  const float4* in = (const float4*)(dist + row * 2048);
  const int t = threadIdx.x;
  float4 v0 = in[t];
  float4 v1 = in[t + 256];

  float m = fmaxf(fmaxf(fmaxf(v0.x, v0.y), fmaxf(v0.z, v0.w)),
                  fmaxf(fmaxf(v1.x, v1.y), fmaxf(v1.z, v1.w)));
#pragma unroll
  for (int off = 32; off > 0; off >>= 1)
    m = fmaxf(m, __shfl_xor(m, off, 64));

  __shared__ float redm[4];
  __shared__ float reds[4];
  if ((t & 63) == 0) redm[t >> 6] = m;
  __syncthreads();
  m = fmaxf(fmaxf(redm[0], redm[1]), fmaxf(redm[2], redm[3]));

  float e[8];
  e[0] = __expf(v0.x - m); e[1] = __expf(v0.y - m);
  e[2] = __expf(v0.z - m); e[3] = __expf(v0.w - m);
  e[4] = __expf(v1.x - m); e[5] = __expf(v1.y - m);
  e[6] = __expf(v1.z - m); e[7] = __expf(v1.w - m);

  float s = ((e[0] + e[1]) + (e[2] + e[3])) + ((e[4] + e[5]) + (e[6] + e[7]));
#pragma unroll
  for (int off = 32; off > 0; off >>= 1)
    s += __shfl_xor(s, off, 64);
  if ((t & 63) == 0) reds[t >> 6] = s;
  __syncthreads();
  s = (reds[0] + reds[1]) + (reds[2] + reds[3]);

  const float inv = 1.0f / s;
  ushort4 o0, o1;
  o0.x = f32_to_bf16(e[0] * inv); o0.y = f32_to_bf16(e[1] * inv);
  o0.z = f32_to_bf16(e[2] * inv); o0.w = f32_to_bf16(e[3] * inv);
  o1.x = f32_to_bf16(e[4] * inv); o1.y = f32_to_bf16(e[5] * inv);
  o1.z = f32_to_bf16(e[6] * inv); o1.w = f32_to_bf16(e[7] * inv);
  *(ushort4*)(attn + row * 2048 + t * 4) = o0;
  *(ushort4*)(attn + row * 2048 + 1024 + t * 4) = o1;
}

// Fused cast of Wq,Wk,Wv,Wo (1M elems each) + x (8M elems) -> contiguous bf16.
__global__ __launch_bounds__(256)
void cast_all(const float* __restrict__ Wq, const float* __restrict__ Wk,
              const float* __restrict__ Wv, const float* __restrict__ Wo,
              const float* __restrict__ x, unsigned short* __restrict__ dst) {
  const long i = ((long)blockIdx.x * 256 + threadIdx.x) * 4;
  const float* src;
  long off;
  if (i < 4194304) {
    const int which = (int)(i >> 20);
    src = (which == 0) ? Wq : (which == 1) ? Wk : (which == 2) ? Wv : Wo;
    off = i & 1048575;
  } else {
    src = x;
    off = i - 4194304;
  }
  float4 v = *(const float4*)(src + off);
  ushort4 o;
  o.x = f32_to_bf16(v.x); o.y = f32_to_bf16(v.y);
  o.z = f32_to_bf16(v.z); o.w = f32_to_bf16(v.w);
  *(ushort4*)(dst + i) = o;
}

extern "C" void kernel_launch(void* const* d_in, const int* in_sizes, int n_in,
                              void* d_out, int out_size, void* d_ws, size_t ws_size,
                              hipStream_t stream) {
  const float* x  = (const float*)d_in[0];
  const float* Wq = (const float*)d_in[1];
  const float* Wk = (const float*)d_in[2];
  const float* Wv = (const float*)d_in[3];
  const float* Wo = (const float*)d_in[4];

  const long Bn = 4, S = 2048, D = 1024;
  const long MS = Bn * S;               // 8192

  float* out_p  = (float*)d_out;        // [B,S,D] = 8192x1024 fp32
  float* weight = out_p + MS * D;       // [B,S,S] = 4x2048x2048 fp32

  // workspace layout (ushort elements):
  unsigned short* Wqb = (unsigned short*)d_ws;   // [2048,1024]: Wq rows then Wk rows
  unsigned short* Wvb = Wqb + 2 * D * D;
  unsigned short* Wob = Wvb + D * D;
  unsigned short* xb  = Wob + D * D;    // [8192,1024]
  unsigned short* qk  = xb + MS * D;    // [8192,2048]: cols 0..1023 = q, 1024.. = k
  unsigned short* vtb = qk + MS * 2048; // [1024][8192]  (vT, cols = b*2048 + s)
  unsigned short* attn = qk;            // alias (qk dead after dist)
  unsigned short* ctx  = xb;            // alias (xb dead after v GEMM)

  cast_all<<<12288, 256, 0, stream>>>(Wq, Wk, Wv, Wo, x, Wqb);

  // qk = x [Wq;Wk]^T  (8192 x 2048 x 1024)               grid 1024
  gemm_bt<0><<<dim3(64, 16, 1), 256, 0, stream>>>(xb, Wqb, qk, 8192, 2048, 1024,
                                                  1024, 1024, 2048, 0, 0, 0, 1.f);
  // vT = Wv x^T : M=1024, N=8192 (all batches merged)    grid 512
  gemm_bt<0><<<dim3(8, 64, 1), 256, 0, stream>>>(Wvb, xb, vtb, 1024, 8192, 1024,
                                                 1024, 1024, 8192, 0, 0, 0, 1.f);
  // dist[b] = scale * q[b] k[b]^T -> fp32                grid 1024
  gemm_bt<2><<<dim3(16, 16, 4), 256, 0, stream>>>(qk, qk + 1024, weight, 2048, 2048, 1024,
                                                  2048, 2048, 2048,
                                                  S * 2048, S * 2048, S * S,
                                                  0.04419417382415922f);
  // attn = softmax(dist) -> bf16
  softmax_rows<<<(int)(Bn * S), 256, 0, stream>>>(weight, attn);
  // ctx[b] = attn[b] vT[:, b*2048:]^T : M=2048, N=1024, K=2048   grid 512
  gemm_bt<0><<<dim3(16, 8, 4), 256, 0, stream>>>(attn, vtb, ctx, 2048, 1024, 2048,
                                                 2048, 8192, 1024,
                                                 S * S, 2048, S * D, 1.f);
  // out = ctx Wo^T -> fp32                               grid 512
  gemm_bt<2><<<dim3(64, 8, 1), 256, 0, stream>>>(ctx, Wob, out_p, 8192, 1024, 1024,
                                                 1024, 1024, 1024, 0, 0, 0, 1.f);
}